// Round 13
// baseline (110.127 us; speedup 1.0000x reference)
//
#include <hip/hip_runtime.h>

typedef short bf16x8 __attribute__((ext_vector_type(8)));
typedef float f32x16 __attribute__((ext_vector_type(16)));

__device__ __forceinline__ unsigned short f2bf(float f) {
  unsigned int x = __float_as_uint(f);
  x += 0x7fffu + ((x >> 16) & 1u);
  return (unsigned short)(x >> 16);
}
__device__ __forceinline__ float bf2f(unsigned short u) {
  return __uint_as_float(((unsigned int)u) << 16);
}

// rocPRIM-pattern wave64 sum via DPP (VALU-only). Total lands in lane 63.
__device__ __forceinline__ float dpp_add(float x) {
  x += __int_as_float(__builtin_amdgcn_update_dpp(0, __float_as_int(x), 0x111, 0xf, 0xf, false)); // row_shr:1
  x += __int_as_float(__builtin_amdgcn_update_dpp(0, __float_as_int(x), 0x112, 0xf, 0xf, false)); // row_shr:2
  x += __int_as_float(__builtin_amdgcn_update_dpp(0, __float_as_int(x), 0x114, 0xf, 0xe, false)); // row_shr:4
  x += __int_as_float(__builtin_amdgcn_update_dpp(0, __float_as_int(x), 0x118, 0xf, 0xc, false)); // row_shr:8
  x += __int_as_float(__builtin_amdgcn_update_dpp(0, __float_as_int(x), 0x142, 0xa, 0xf, false)); // row_bcast:15
  x += __int_as_float(__builtin_amdgcn_update_dpp(0, __float_as_int(x), 0x143, 0xc, 0xf, false)); // row_bcast:31
  return x;
}
// full-wave sum broadcast to all lanes (via SGPR readlane of lane 63)
__device__ __forceinline__ float wave_sum(float x) {
  return __int_as_float(__builtin_amdgcn_readlane(__float_as_int(dpp_add(x)), 63));
}

#define GLD_LDS16(gp, lp)                                                     \
  __builtin_amdgcn_global_load_lds(                                           \
      (const __attribute__((address_space(1))) void*)(gp),                    \
      (__attribute__((address_space(3))) void*)(lp), 16, 0, 0)

// ---------------------------------------------------------------------------
// K0: W_sub (1024x1024 f32, row-major [k][n]) -> Wt bf16 [n][k]  (R1-proven)
// ---------------------------------------------------------------------------
__global__ __launch_bounds__(256) void k_prep_w(
    const float* __restrict__ W, unsigned short* __restrict__ Wt)
{
  __shared__ float tile[32][33];
  const int bn = blockIdx.x, bk = blockIdx.y;
  const int tx = threadIdx.x & 31, ty = threadIdx.x >> 5;
#pragma unroll
  for (int r = ty; r < 32; r += 8)
    tile[r][tx] = W[(size_t)(bk * 32 + r) * 1024 + bn * 32 + tx];
  __syncthreads();
#pragma unroll
  for (int r = ty; r < 32; r += 8)
    Wt[(size_t)(bn * 32 + r) * 1024 + bk * 32 + tx] = f2bf(tile[tx][r]);
}

// ---------------------------------------------------------------------------
// K1 (fused, self-sufficient blocks — NO inter-block communication):
// 256 blocks x 512 threads (8 waves); block owns GEMM rows [blk*32, blk*32+32).
// Phase 1: each wave LN-processes 4 rows (wave-local DPP reductions, no
//          barriers), havg -> LDS (bf16, padded stride), beta -> LDS.
// Phase 2: one __syncthreads.
// Phase 3: GEMM 32x1024x1024: A resident in LDS; B = whole Wt streamed in
//          32 k-steps into WAVE-PRIVATE Bs groups (8KB each) => no barriers,
//          only wave-local vmcnt(0). 32x32x16 MFMA (R8-verified layouts).
// Phase 4: epilogue out[m][i][n] = beta*h_o + havg (havg read from LDS).
// ---------------------------------------------------------------------------
#define AP 1028  // Ahs row stride in ushorts (pad 4 -> 2-way LDS conflicts max)

__global__ __launch_bounds__(512) void k_fused(
    const float* __restrict__ h,       // (8192, 4, 1024)
    const float* __restrict__ ln_g,    // (1024)
    const float* __restrict__ ln_b,    // (1024)
    const float* __restrict__ dbf,     // (1024, 4)
    const float* __restrict__ dbs,     // (1)
    const float* __restrict__ sbeta,   // (4)
    const unsigned short* __restrict__ Wt,  // (1024,1024) bf16 [n][k]
    float* __restrict__ out)           // (8192, 4, 1024)
{
  __shared__ unsigned short Ahs[32 * AP];      // 65,792 B  (havg, bf16)
  __shared__ unsigned short Bs[8 * 128 * 32];  // 65,536 B  (8 wave-private groups)
  __shared__ float bet[32][4];                 // 512 B
  const int t = threadIdx.x;
  const int wid = t >> 6, lane = t & 63;
  const int blk = blockIdx.x;

  // ================= Phase 1: LN + havg + beta (wave-local) ================
  {
    const float sc = dbs[0];
    const float4 sb4 = *(const float4*)sbeta;
    const float sbv[4] = {sb4.x, sb4.y, sb4.z, sb4.w};
#pragma unroll
    for (int rr = 0; rr < 4; ++rr) {
      const int row = wid * 4 + rr;
      const float* hr = h + (size_t)(blk * 32 + row) * 4096;
      float x[4][4][4];  // [chunk][n][j], d = chunk*256 + lane*4 + j
      float sum[4] = {0.f, 0.f, 0.f, 0.f}, sq[4] = {0.f, 0.f, 0.f, 0.f};
#pragma unroll
      for (int c = 0; c < 4; ++c) {
        const int d0 = c * 256 + lane * 4;
#pragma unroll
        for (int n = 0; n < 4; ++n) {
          const float4 v = *(const float4*)(hr + n * 1024 + d0);
          x[c][n][0] = v.x; x[c][n][1] = v.y; x[c][n][2] = v.z; x[c][n][3] = v.w;
          sum[n] += v.x + v.y + v.z + v.w;
          sq[n] += v.x * v.x + v.y * v.y + v.z * v.z + v.w * v.w;
        }
      }
      float mean[4], rstd[4];
#pragma unroll
      for (int n = 0; n < 4; ++n) {
        const float S = wave_sum(sum[n]);
        const float Q = wave_sum(sq[n]);
        const float m = S * (1.0f / 1024.0f);
        mean[n] = m;
        rstd[n] = rsqrtf(Q * (1.0f / 1024.0f) - m * m + 1e-5f);
      }
      float bp[4] = {0.f, 0.f, 0.f, 0.f};
#pragma unroll
      for (int c = 0; c < 4; ++c) {
        const int d0 = c * 256 + lane * 4;
        const float4 g4 = *(const float4*)(ln_g + d0);
        const float4 b4 = *(const float4*)(ln_b + d0);
        const float gv[4] = {g4.x, g4.y, g4.z, g4.w};
        const float bv[4] = {b4.x, b4.y, b4.z, b4.w};
        ushort4 pk;
        unsigned short* pku = (unsigned short*)&pk;
#pragma unroll
        for (int j = 0; j < 4; ++j) {
          float sh = 0.f, sn = 0.f;
#pragma unroll
          for (int n = 0; n < 4; ++n) {
            sh += x[c][n][j];
            sn += (x[c][n][j] - mean[n]) * rstd[n];
          }
          pku[j] = f2bf(0.25f * sh);                       // havg
          const float nmj = 0.25f * sn * gv[j] + bv[j];    // norm_h_mean
          const float4 wv = *(const float4*)(dbf + (size_t)(d0 + j) * 4);
          bp[0] += nmj * wv.x; bp[1] += nmj * wv.y;
          bp[2] += nmj * wv.z; bp[3] += nmj * wv.w;
        }
        *(ushort4*)(&Ahs[row * AP + d0]) = pk;
      }
      float be[4];
#pragma unroll
      for (int cc = 0; cc < 4; ++cc)
        be[cc] = tanhf(wave_sum(bp[cc])) * sc + sbv[cc];
      if (lane == 0) {
        bet[row][0] = be[0]; bet[row][1] = be[1];
        bet[row][2] = be[2]; bet[row][3] = be[3];
      }
    }
  }
  __syncthreads();  // the ONLY block-wide barrier

  // ================= Phase 3: GEMM (wave-private B staging) ================
  const int l31 = lane & 31, kh = lane >> 5;
  // staging source: n = wid*128 + g*16 + (lane>>2), kpart = lane&3
  const unsigned short* gB0 =
      Wt + (size_t)(wid * 128 + (lane >> 2)) * 1024 + (lane & 3) * 8;
  char* ldsB = (char*)Bs + wid * 8192;  // wave-private group (wave-uniform)

  f32x16 acc[4] = {};
  for (int kt = 0; kt < 32; ++kt) {
    const int k0 = kt * 32;
    // prior ds_reads drained before overwriting Bs (wave-local ordering)
    asm volatile("s_waitcnt lgkmcnt(0)" ::: "memory");
    __builtin_amdgcn_sched_barrier(0);
#pragma unroll
    for (int g = 0; g < 8; ++g)
      GLD_LDS16(gB0 + g * 16384 + k0, ldsB + g * 1024);
    asm volatile("s_waitcnt vmcnt(0)" ::: "memory");
    __builtin_amdgcn_sched_barrier(0);
    bf16x8 a[2], b[4][2];
#pragma unroll
    for (int s16 = 0; s16 < 2; ++s16)
      a[s16] = *(const bf16x8*)((const char*)Ahs + l31 * (AP * 2) +
                                (k0 + s16 * 16 + kh * 8) * 2);
#pragma unroll
    for (int ni = 0; ni < 4; ++ni)
#pragma unroll
      for (int s16 = 0; s16 < 2; ++s16)
        b[ni][s16] = *(const bf16x8*)(ldsB + (ni * 32 + l31) * 64 +
                                      s16 * 32 + kh * 16);
#pragma unroll
    for (int s16 = 0; s16 < 2; ++s16)
#pragma unroll
      for (int ni = 0; ni < 4; ++ni)
        acc[ni] = __builtin_amdgcn_mfma_f32_32x32x16_bf16(
            a[s16], b[ni][s16], acc[ni], 0, 0, 0);
  }

  // ================= Phase 4: epilogue =====================================
  // 32x32 C/D: col = l31 (+cbase), row = (reg&3) + 8*(reg>>2) + 4*kh
#pragma unroll
  for (int ni = 0; ni < 4; ++ni) {
    const int cbase = wid * 128 + ni * 32 + l31;
#pragma unroll
    for (int reg = 0; reg < 16; ++reg) {
      const int row = (reg & 3) + 8 * (reg >> 2) + 4 * kh;
      const float4 be = *(const float4*)&bet[row][0];
      const float hv = bf2f(Ahs[row * AP + cbase]);
      const float ho = acc[ni][reg];
      float* o = out + (size_t)(blk * 32 + row) * 4096 + cbase;
      o[0]    = be.x * ho + hv;
      o[1024] = be.y * ho + hv;
      o[2048] = be.z * ho + hv;
      o[3072] = be.w * ho + hv;
    }
  }
}

extern "C" void kernel_launch(void* const* d_in, const int* in_sizes, int n_in,
                              void* d_out, int out_size, void* d_ws, size_t ws_size,
                              hipStream_t stream) {
  const float* h     = (const float*)d_in[0];
  // d_in[1] static_alpha, d_in[3] dynamic_alpha_fn, d_in[4] dynamic_alpha_scale:
  // dead — Sinkhorn output is exactly 1/n for this broadcast-structured alpha.
  const float* sbeta = (const float*)d_in[2];
  const float* dbf   = (const float*)d_in[5];
  const float* dbs   = (const float*)d_in[6];
  const float* ln_g  = (const float*)d_in[7];
  const float* ln_b  = (const float*)d_in[8];
  const float* W     = (const float*)d_in[9];
  float* out = (float*)d_out;

  unsigned short* Wt = (unsigned short*)d_ws;  // 2 MB

  hipLaunchKernelGGL(k_prep_w, dim3(32, 32), dim3(256), 0, stream, W, Wt);
  hipLaunchKernelGGL(k_fused, dim3(256), dim3(512), 0, stream,
                     h, ln_g, ln_b, dbf, dbs, sbeta, Wt, out);
}

// Round 14
// 103.279 us; speedup vs baseline: 1.0663x; 1.0663x over previous
//
#include <hip/hip_runtime.h>

typedef short bf16x8 __attribute__((ext_vector_type(8)));
typedef float f32x4 __attribute__((ext_vector_type(4)));

__device__ __forceinline__ unsigned short f2bf(float f) {
  unsigned int x = __float_as_uint(f);
  x += 0x7fffu + ((x >> 16) & 1u);
  return (unsigned short)(x >> 16);
}
__device__ __forceinline__ float bf2f(unsigned short u) {
  return __uint_as_float(((unsigned int)u) << 16);
}

// rocPRIM-pattern wave64 sum via DPP (VALU-only, no LDS pipe). Sum -> lane 63.
__device__ __forceinline__ float dpp_add(float x) {
  x += __int_as_float(__builtin_amdgcn_update_dpp(0, __float_as_int(x), 0x111, 0xf, 0xf, false)); // row_shr:1
  x += __int_as_float(__builtin_amdgcn_update_dpp(0, __float_as_int(x), 0x112, 0xf, 0xf, false)); // row_shr:2
  x += __int_as_float(__builtin_amdgcn_update_dpp(0, __float_as_int(x), 0x114, 0xf, 0xe, false)); // row_shr:4
  x += __int_as_float(__builtin_amdgcn_update_dpp(0, __float_as_int(x), 0x118, 0xf, 0xc, false)); // row_shr:8
  x += __int_as_float(__builtin_amdgcn_update_dpp(0, __float_as_int(x), 0x142, 0xa, 0xf, false)); // row_bcast:15
  x += __int_as_float(__builtin_amdgcn_update_dpp(0, __float_as_int(x), 0x143, 0xc, 0xf, false)); // row_bcast:31
  return x;
}

#define GLD_LDS16(gp, lp)                                                     \
  __builtin_amdgcn_global_load_lds(                                           \
      (const __attribute__((address_space(1))) void*)(gp),                    \
      (__attribute__((address_space(3))) void*)(lp), 16, 0, 0)

// ---------------------------------------------------------------------------
// K0 (blocks 0..1023): W_sub f32 [k][n] -> Wt bf16 [n][k] transpose (first).
// K1 (blocks 1024..9215): per-(b,s) LN stats + h_avg (bf16) + beta GEMV.
// (R10-proven — FROZEN. Launched TWICE this round as a timing probe: the
//  second launch recomputes identical values; dur delta = k_pre duration.)
// ---------------------------------------------------------------------------
__global__ __launch_bounds__(256) void k_pre(
    const float* __restrict__ h,       // (8192, 4, 1024)
    const float* __restrict__ ln_g,    // (1024)
    const float* __restrict__ ln_b,    // (1024)
    const float* __restrict__ dbf,     // (1024, 4)
    const float* __restrict__ dbs,     // (1)
    const float* __restrict__ sbeta,   // (4)
    const float* __restrict__ W,       // (1024, 1024)
    unsigned short* __restrict__ havg, // (8192, 1024) bf16
    float* __restrict__ beta_out,      // (8192, 4)
    unsigned short* __restrict__ Wt)   // (1024, 1024) bf16 transposed
{
  __shared__ float shmem[32 * 33];
  const int t = threadIdx.x;

  if (blockIdx.x < 1024) {
    // ---- W transpose (runs first) ----
    const int b = blockIdx.x;
    const int bn = b & 31, bk = b >> 5;
    float (*tile)[33] = (float (*)[33])shmem;
    const int tx = t & 31, ty = t >> 5;
#pragma unroll
    for (int r = ty; r < 32; r += 8)
      tile[r][tx] = W[(size_t)(bk * 32 + r) * 1024 + bn * 32 + tx];
    __syncthreads();
#pragma unroll
    for (int r = ty; r < 32; r += 8)
      Wt[(size_t)(bn * 32 + r) * 1024 + bk * 32 + tx] = f2bf(tile[tx][r]);
    return;
  }

  const int bs = blockIdx.x - 1024;
  const int lane = t & 63, wid = t >> 6;
  float (*sm)[8] = (float (*)[8])shmem;
  const float* hrow = h + (size_t)bs * 4096;
  const int d0 = t * 4;

  float x[4][4];
  float red[8];
#pragma unroll
  for (int n = 0; n < 4; ++n) {
    float4 v = *(const float4*)(hrow + n * 1024 + d0);
    x[n][0] = v.x; x[n][1] = v.y; x[n][2] = v.z; x[n][3] = v.w;
    red[n] = v.x + v.y + v.z + v.w;
    red[4 + n] = v.x * v.x + v.y * v.y + v.z * v.z + v.w * v.w;
  }
#pragma unroll
  for (int k = 0; k < 8; ++k) red[k] = dpp_add(red[k]);
  if (lane == 63) {
#pragma unroll
    for (int k = 0; k < 8; ++k) sm[wid][k] = red[k];
  }
  __syncthreads();
  float mean[4], rstd[4];
#pragma unroll
  for (int n = 0; n < 4; ++n) {
    float s = sm[0][n] + sm[1][n] + sm[2][n] + sm[3][n];
    float sq = sm[0][4 + n] + sm[1][4 + n] + sm[2][4 + n] + sm[3][4 + n];
    float m = s * (1.0f / 1024.0f);
    float var = sq * (1.0f / 1024.0f) - m * m;
    mean[n] = m;
    rstd[n] = rsqrtf(var + 1e-5f);
  }
  const float4 g4 = *(const float4*)(ln_g + d0);
  const float4 b4 = *(const float4*)(ln_b + d0);
  const float gg[4] = {g4.x, g4.y, g4.z, g4.w};
  const float bb[4] = {b4.x, b4.y, b4.z, b4.w};

  float nm[4];
  ushort4 pack;
  unsigned short* pk = (unsigned short*)&pack;
#pragma unroll
  for (int j = 0; j < 4; ++j) {
    float sh = 0.f, sn = 0.f;
#pragma unroll
    for (int n = 0; n < 4; ++n) {
      sh += x[n][j];
      sn += (x[n][j] - mean[n]) * rstd[n];
    }
    pk[j] = f2bf(0.25f * sh);               // h_avg = mix_h row (i-independent)
    nm[j] = 0.25f * sn * gg[j] + bb[j];     // norm_h_mean
  }
  *(ushort4*)(havg + (size_t)bs * 1024 + d0) = pack;

  // beta = tanh(nm @ dbf) * scale + static_beta
  float a4[4] = {0.f, 0.f, 0.f, 0.f};
#pragma unroll
  for (int j = 0; j < 4; ++j) {
    const float4 w = *(const float4*)(dbf + (size_t)(d0 + j) * 4);
    a4[0] += nm[j] * w.x; a4[1] += nm[j] * w.y;
    a4[2] += nm[j] * w.z; a4[3] += nm[j] * w.w;
  }
#pragma unroll
  for (int c = 0; c < 4; ++c) a4[c] = dpp_add(a4[c]);
  __syncthreads();  // all stats reads done before sm re-write
  if (lane == 63) {
#pragma unroll
    for (int c = 0; c < 4; ++c) sm[wid][c] = a4[c];
  }
  __syncthreads();
  if (t == 0) {
    const float sc = dbs[0];
#pragma unroll
    for (int c = 0; c < 4; ++c) {
      float dot = sm[0][c] + sm[1][c] + sm[2][c] + sm[3][c];
      beta_out[(size_t)bs * 4 + c] = tanhf(dot) * sc + sbeta[c];
    }
  }
}

// ---------------------------------------------------------------------------
// K2: h_o = h_avg @ W  (M=8192, N=1024, K=1024, 128x128 tile, BK=64)
//     R10-proven — FROZEN this round (measurement round).
//     epilogue: out[m][i][n] = beta[m][i]*h_o[m][n] + h_avg[m][n]
// ---------------------------------------------------------------------------
__global__ __launch_bounds__(256) void k_gemm_ep(
    const unsigned short* __restrict__ A,   // (8192,1024) bf16  h_avg
    const unsigned short* __restrict__ Bt,  // (1024,1024) bf16  Wt[n][k]
    const float* __restrict__ beta4,        // (8192,4)
    float* __restrict__ out)                // (8192,4,1024)
{
  __shared__ unsigned short As[2][128][32];
  __shared__ unsigned short Bs[2][128][32];
  const int t = threadIdx.x;
  const int wid = t >> 6, lane = t & 63;
  const int mblk = blockIdx.x, nblk = blockIdx.y;
  const int wr = wid >> 1, wc = wid & 1;      // 2x2 waves, 64x64 each
  const int l15 = lane & 15, kg = lane >> 4;  // fragment coords

  f32x4 acc[4][4] = {};

  const int srow = t >> 2;
  const int sk8 = (t & 3) * 8;
  const unsigned short* gA = A + (size_t)(mblk * 128 + srow) * 1024 + sk8;
  const unsigned short* gB = Bt + (size_t)(nblk * 128 + srow) * 1024 + sk8;
  char* ldsA = (char*)As + wid * 1024;  // wave-uniform base
  char* ldsB = (char*)Bs + wid * 1024;

  for (int kt2 = 0; kt2 < 16; ++kt2) {
    const int ko = kt2 * 64;
    // stage BOTH 32-wide sub-tiles, then a single drain barrier
    GLD_LDS16(gA + ko, ldsA);
    GLD_LDS16(gA + 64 * 1024 + ko, ldsA + 4096);
    GLD_LDS16(gA + ko + 32, ldsA + 8192);
    GLD_LDS16(gA + 64 * 1024 + ko + 32, ldsA + 8192 + 4096);
    GLD_LDS16(gB + ko, ldsB);
    GLD_LDS16(gB + 64 * 1024 + ko, ldsB + 4096);
    GLD_LDS16(gB + ko + 32, ldsB + 8192);
    GLD_LDS16(gB + 64 * 1024 + ko + 32, ldsB + 8192 + 4096);
    __syncthreads();
#pragma unroll
    for (int sub = 0; sub < 2; ++sub) {
      bf16x8 a[4], b[4];
#pragma unroll
      for (int mi = 0; mi < 4; ++mi)
        a[mi] = *(const bf16x8*)(&As[sub][wr * 64 + mi * 16 + l15][kg * 8]);
#pragma unroll
      for (int ni = 0; ni < 4; ++ni)
        b[ni] = *(const bf16x8*)(&Bs[sub][wc * 64 + ni * 16 + l15][kg * 8]);
#pragma unroll
      for (int mi = 0; mi < 4; ++mi)
#pragma unroll
        for (int ni = 0; ni < 4; ++ni)
          acc[mi][ni] =
              __builtin_amdgcn_mfma_f32_16x16x32_bf16(a[mi], b[ni], acc[mi][ni], 0, 0, 0);
    }
    __syncthreads();
  }

  // epilogue: D row = 4*(lane>>4)+reg, col = lane&15 within each 16x16 frag
  const int rbase = mblk * 128 + wr * 64 + kg * 4;
  const int cbase = nblk * 128 + wc * 64 + l15;
#pragma unroll
  for (int mi = 0; mi < 4; ++mi) {
    float4 be[4];
#pragma unroll
    for (int r = 0; r < 4; ++r)
      be[r] = *(const float4*)(beta4 + (size_t)(rbase + mi * 16 + r) * 4);
#pragma unroll
    for (int ni = 0; ni < 4; ++ni) {
      const int col = cbase + ni * 16;
#pragma unroll
      for (int r = 0; r < 4; ++r) {
        const int row = rbase + mi * 16 + r;
        const float ho = acc[mi][ni][r];
        const float hv = bf2f(A[(size_t)row * 1024 + col]);
        const float4 bq = be[r];
        float* o = out + (size_t)row * 4096 + col;
        o[0]    = bq.x * ho + hv;
        o[1024] = bq.y * ho + hv;
        o[2048] = bq.z * ho + hv;
        o[3072] = bq.w * ho + hv;
      }
    }
  }
}

extern "C" void kernel_launch(void* const* d_in, const int* in_sizes, int n_in,
                              void* d_out, int out_size, void* d_ws, size_t ws_size,
                              hipStream_t stream) {
  const float* h     = (const float*)d_in[0];
  // d_in[1] static_alpha, d_in[3] dynamic_alpha_fn, d_in[4] dynamic_alpha_scale:
  // dead — Sinkhorn output is exactly 1/n for this broadcast-structured alpha.
  const float* sbeta = (const float*)d_in[2];
  const float* dbf   = (const float*)d_in[5];
  const float* dbs   = (const float*)d_in[6];
  const float* ln_g  = (const float*)d_in[7];
  const float* ln_b  = (const float*)d_in[8];
  const float* W     = (const float*)d_in[9];
  float* out = (float*)d_out;

  char* ws = (char*)d_ws;
  unsigned short* havg = (unsigned short*)ws;                  // 16 MB
  unsigned short* Wt   = (unsigned short*)(ws + (16u << 20));  // 2 MB
  float* beta          = (float*)(ws + (18u << 20));           // 128 KB

  // MEASUREMENT ROUND: k_pre launched twice (idempotent — identical rewrite).
  // dur_us - 81.4 = k_pre duration. Output unaffected.
  hipLaunchKernelGGL(k_pre, dim3(1024 + 8192), dim3(256), 0, stream,
                     h, ln_g, ln_b, dbf, dbs, sbeta, W, havg, beta, Wt);
  hipLaunchKernelGGL(k_pre, dim3(1024 + 8192), dim3(256), 0, stream,
                     h, ln_g, ln_b, dbf, dbs, sbeta, W, havg, beta, Wt);
  hipLaunchKernelGGL(k_gemm_ep, dim3(64, 8), dim3(256), 0, stream,
                     havg, Wt, beta, out);
}

// Round 15
// 83.511 us; speedup vs baseline: 1.3187x; 1.2367x over previous
//
#include <hip/hip_runtime.h>

typedef short bf16x8 __attribute__((ext_vector_type(8)));
typedef float f32x4 __attribute__((ext_vector_type(4)));

__device__ __forceinline__ unsigned short f2bf(float f) {
  unsigned int x = __float_as_uint(f);
  x += 0x7fffu + ((x >> 16) & 1u);
  return (unsigned short)(x >> 16);
}
__device__ __forceinline__ float bf2f(unsigned short u) {
  return __uint_as_float(((unsigned int)u) << 16);
}

// rocPRIM-pattern wave64 sum via DPP (VALU-only, no LDS pipe). Sum -> lane 63.
__device__ __forceinline__ float dpp_add(float x) {
  x += __int_as_float(__builtin_amdgcn_update_dpp(0, __float_as_int(x), 0x111, 0xf, 0xf, false)); // row_shr:1
  x += __int_as_float(__builtin_amdgcn_update_dpp(0, __float_as_int(x), 0x112, 0xf, 0xf, false)); // row_shr:2
  x += __int_as_float(__builtin_amdgcn_update_dpp(0, __float_as_int(x), 0x114, 0xf, 0xe, false)); // row_shr:4
  x += __int_as_float(__builtin_amdgcn_update_dpp(0, __float_as_int(x), 0x118, 0xf, 0xc, false)); // row_shr:8
  x += __int_as_float(__builtin_amdgcn_update_dpp(0, __float_as_int(x), 0x142, 0xa, 0xf, false)); // row_bcast:15
  x += __int_as_float(__builtin_amdgcn_update_dpp(0, __float_as_int(x), 0x143, 0xc, 0xf, false)); // row_bcast:31
  return x;
}

#define GLD_LDS16(gp, lp)                                                     \
  __builtin_amdgcn_global_load_lds(                                           \
      (const __attribute__((address_space(1))) void*)(gp),                    \
      (__attribute__((address_space(3))) void*)(lp), 16, 0, 0)

// ---------------------------------------------------------------------------
// K0 (blocks 0..1023): W_sub f32 [k][n] -> Wt bf16 [n][k] transpose (first).
// K1 (blocks 1024..9215): per-(b,s) LN stats + h_avg (bf16) + beta GEMV.
// (R10-proven — FROZEN. Measured R14: 21.9 µs ≈ HBM floor.)
// ---------------------------------------------------------------------------
__global__ __launch_bounds__(256) void k_pre(
    const float* __restrict__ h,       // (8192, 4, 1024)
    const float* __restrict__ ln_g,    // (1024)
    const float* __restrict__ ln_b,    // (1024)
    const float* __restrict__ dbf,     // (1024, 4)
    const float* __restrict__ dbs,     // (1)
    const float* __restrict__ sbeta,   // (4)
    const float* __restrict__ W,       // (1024, 1024)
    unsigned short* __restrict__ havg, // (8192, 1024) bf16
    float* __restrict__ beta_out,      // (8192, 4)
    unsigned short* __restrict__ Wt)   // (1024, 1024) bf16 transposed
{
  __shared__ float shmem[32 * 33];
  const int t = threadIdx.x;

  if (blockIdx.x < 1024) {
    // ---- W transpose (runs first) ----
    const int b = blockIdx.x;
    const int bn = b & 31, bk = b >> 5;
    float (*tile)[33] = (float (*)[33])shmem;
    const int tx = t & 31, ty = t >> 5;
#pragma unroll
    for (int r = ty; r < 32; r += 8)
      tile[r][tx] = W[(size_t)(bk * 32 + r) * 1024 + bn * 32 + tx];
    __syncthreads();
#pragma unroll
    for (int r = ty; r < 32; r += 8)
      Wt[(size_t)(bn * 32 + r) * 1024 + bk * 32 + tx] = f2bf(tile[tx][r]);
    return;
  }

  const int bs = blockIdx.x - 1024;
  const int lane = t & 63, wid = t >> 6;
  float (*sm)[8] = (float (*)[8])shmem;
  const float* hrow = h + (size_t)bs * 4096;
  const int d0 = t * 4;

  float x[4][4];
  float red[8];
#pragma unroll
  for (int n = 0; n < 4; ++n) {
    float4 v = *(const float4*)(hrow + n * 1024 + d0);
    x[n][0] = v.x; x[n][1] = v.y; x[n][2] = v.z; x[n][3] = v.w;
    red[n] = v.x + v.y + v.z + v.w;
    red[4 + n] = v.x * v.x + v.y * v.y + v.z * v.z + v.w * v.w;
  }
#pragma unroll
  for (int k = 0; k < 8; ++k) red[k] = dpp_add(red[k]);
  if (lane == 63) {
#pragma unroll
    for (int k = 0; k < 8; ++k) sm[wid][k] = red[k];
  }
  __syncthreads();
  float mean[4], rstd[4];
#pragma unroll
  for (int n = 0; n < 4; ++n) {
    float s = sm[0][n] + sm[1][n] + sm[2][n] + sm[3][n];
    float sq = sm[0][4 + n] + sm[1][4 + n] + sm[2][4 + n] + sm[3][4 + n];
    float m = s * (1.0f / 1024.0f);
    float var = sq * (1.0f / 1024.0f) - m * m;
    mean[n] = m;
    rstd[n] = rsqrtf(var + 1e-5f);
  }
  const float4 g4 = *(const float4*)(ln_g + d0);
  const float4 b4 = *(const float4*)(ln_b + d0);
  const float gg[4] = {g4.x, g4.y, g4.z, g4.w};
  const float bb[4] = {b4.x, b4.y, b4.z, b4.w};

  float nm[4];
  ushort4 pack;
  unsigned short* pk = (unsigned short*)&pack;
#pragma unroll
  for (int j = 0; j < 4; ++j) {
    float sh = 0.f, sn = 0.f;
#pragma unroll
    for (int n = 0; n < 4; ++n) {
      sh += x[n][j];
      sn += (x[n][j] - mean[n]) * rstd[n];
    }
    pk[j] = f2bf(0.25f * sh);               // h_avg = mix_h row (i-independent)
    nm[j] = 0.25f * sn * gg[j] + bb[j];     // norm_h_mean
  }
  *(ushort4*)(havg + (size_t)bs * 1024 + d0) = pack;

  // beta = tanh(nm @ dbf) * scale + static_beta
  float a4[4] = {0.f, 0.f, 0.f, 0.f};
#pragma unroll
  for (int j = 0; j < 4; ++j) {
    const float4 w = *(const float4*)(dbf + (size_t)(d0 + j) * 4);
    a4[0] += nm[j] * w.x; a4[1] += nm[j] * w.y;
    a4[2] += nm[j] * w.z; a4[3] += nm[j] * w.w;
  }
#pragma unroll
  for (int c = 0; c < 4; ++c) a4[c] = dpp_add(a4[c]);
  __syncthreads();  // all stats reads done before sm re-write
  if (lane == 63) {
#pragma unroll
    for (int c = 0; c < 4; ++c) sm[wid][c] = a4[c];
  }
  __syncthreads();
  if (t == 0) {
    const float sc = dbs[0];
#pragma unroll
    for (int c = 0; c < 4; ++c) {
      float dot = sm[0][c] + sm[1][c] + sm[2][c] + sm[3][c];
      beta_out[(size_t)bs * 4 + c] = tanhf(dot) * sc + sbeta[c];
    }
  }
}

// ---------------------------------------------------------------------------
// K2: h_o = h_avg @ W  (M=8192, N=1024, K=1024, 128x128 tile, BK=128)
//     THIS ROUND: 2-way M-SPLIT. Each block computes rows 0-63 over full K,
//     issues their stores (fire-and-forget), then computes rows 64-127 while
//     those stores drain -> ~half the write burst overlaps compute.
//     B restaged per half (L2-cheap). 16 drain barriers total (= R10/R12).
//     LDS 48 KB -> still 2 blocks/CU. Waves 2x2 over 64x128 (32x64 each).
//     epilogue: out[m][i][n] = beta[m][i]*h_o[m][n] + h_avg[m][n]
// ---------------------------------------------------------------------------
__global__ __launch_bounds__(256) void k_gemm_ep(
    const unsigned short* __restrict__ A,   // (8192,1024) bf16  h_avg
    const unsigned short* __restrict__ Bt,  // (1024,1024) bf16  Wt[n][k]
    const float* __restrict__ beta4,        // (8192,4)
    float* __restrict__ out)                // (8192,4,1024)
{
  __shared__ unsigned short As[4][64][32];   // 16 KB (one 64-row half, BK=128)
  __shared__ unsigned short Bs[4][128][32];  // 32 KB
  const int t = threadIdx.x;
  const int wid = t >> 6, lane = t & 63;
  const int mblk = blockIdx.x, nblk = blockIdx.y;
  const int wr = wid >> 1, wc = wid & 1;      // waves 2x2 over 64x128 half
  const int l15 = lane & 15, kg = lane >> 4;  // fragment coords

  const int srow = t >> 2;                    // 0..63 (A) / 0..63 (B lower)
  const int sk8 = (t & 3) * 8;
  const unsigned short* gB = Bt + (size_t)(nblk * 128 + srow) * 1024 + sk8;
  char* ldsA = (char*)As + wid * 1024;  // wave-uniform base
  char* ldsB = (char*)Bs + wid * 1024;

#pragma unroll
  for (int half = 0; half < 2; ++half) {
    const unsigned short* gA =
        A + (size_t)(mblk * 128 + half * 64 + srow) * 1024 + sk8;

    f32x4 acc[2][4] = {};
    for (int kt = 0; kt < 8; ++kt) {
      const int ko = kt * 128;
#pragma unroll
      for (int s = 0; s < 4; ++s) {
        GLD_LDS16(gA + ko + s * 32, ldsA + s * 4096);              // A 64x32
        GLD_LDS16(gB + ko + s * 32, ldsB + s * 8192);              // B rows 0-63
        GLD_LDS16(gB + 64 * 1024 + ko + s * 32, ldsB + s * 8192 + 4096); // 64-127
      }
      __syncthreads();
#pragma unroll
      for (int sub = 0; sub < 4; ++sub) {
        bf16x8 a[2], b[4];
#pragma unroll
        for (int mi = 0; mi < 2; ++mi)
          a[mi] = *(const bf16x8*)(&As[sub][wr * 32 + mi * 16 + l15][kg * 8]);
#pragma unroll
        for (int ni = 0; ni < 4; ++ni)
          b[ni] = *(const bf16x8*)(&Bs[sub][wc * 64 + ni * 16 + l15][kg * 8]);
#pragma unroll
        for (int mi = 0; mi < 2; ++mi)
#pragma unroll
          for (int ni = 0; ni < 4; ++ni)
            acc[mi][ni] =
                __builtin_amdgcn_mfma_f32_16x16x32_bf16(a[mi], b[ni], acc[mi][ni], 0, 0, 0);
      }
      __syncthreads();
    }

    // epilogue for this half — stores are fire-and-forget; they drain
    // while the next half computes.
    const int rbase = mblk * 128 + half * 64 + wr * 32 + kg * 4;
    const int cbase = nblk * 128 + wc * 64 + l15;
#pragma unroll
    for (int mi = 0; mi < 2; ++mi) {
      float4 be[4];
#pragma unroll
      for (int r = 0; r < 4; ++r)
        be[r] = *(const float4*)(beta4 + (size_t)(rbase + mi * 16 + r) * 4);
#pragma unroll
      for (int ni = 0; ni < 4; ++ni) {
        const int col = cbase + ni * 16;
#pragma unroll
        for (int r = 0; r < 4; ++r) {
          const int row = rbase + mi * 16 + r;
          const float ho = acc[mi][ni][r];
          const float hv = bf2f(A[(size_t)row * 1024 + col]);
          const float4 bq = be[r];
          float* o = out + (size_t)row * 4096 + col;
          o[0]    = bq.x * ho + hv;
          o[1024] = bq.y * ho + hv;
          o[2048] = bq.z * ho + hv;
          o[3072] = bq.w * ho + hv;
        }
      }
    }
    if (half == 0) __syncthreads();  // Bs/As reuse guard before restage
  }
}

extern "C" void kernel_launch(void* const* d_in, const int* in_sizes, int n_in,
                              void* d_out, int out_size, void* d_ws, size_t ws_size,
                              hipStream_t stream) {
  const float* h     = (const float*)d_in[0];
  // d_in[1] static_alpha, d_in[3] dynamic_alpha_fn, d_in[4] dynamic_alpha_scale:
  // dead — Sinkhorn output is exactly 1/n for this broadcast-structured alpha.
  const float* sbeta = (const float*)d_in[2];
  const float* dbf   = (const float*)d_in[5];
  const float* dbs   = (const float*)d_in[6];
  const float* ln_g  = (const float*)d_in[7];
  const float* ln_b  = (const float*)d_in[8];
  const float* W     = (const float*)d_in[9];
  float* out = (float*)d_out;

  char* ws = (char*)d_ws;
  unsigned short* havg = (unsigned short*)ws;                  // 16 MB
  unsigned short* Wt   = (unsigned short*)(ws + (16u << 20));  // 2 MB
  float* beta          = (float*)(ws + (18u << 20));           // 128 KB

  hipLaunchKernelGGL(k_pre, dim3(1024 + 8192), dim3(256), 0, stream,
                     h, ln_g, ln_b, dbf, dbs, sbeta, W, havg, beta, Wt);
  hipLaunchKernelGGL(k_gemm_ep, dim3(64, 8), dim3(256), 0, stream,
                     havg, Wt, beta, out);
}

// Round 16
// 83.023 us; speedup vs baseline: 1.3265x; 1.0059x over previous
//
#include <hip/hip_runtime.h>

typedef short bf16x8 __attribute__((ext_vector_type(8)));
typedef float f32x4 __attribute__((ext_vector_type(4)));

__device__ __forceinline__ unsigned short f2bf(float f) {
  unsigned int x = __float_as_uint(f);
  x += 0x7fffu + ((x >> 16) & 1u);
  return (unsigned short)(x >> 16);
}
__device__ __forceinline__ float bf2f(unsigned short u) {
  return __uint_as_float(((unsigned int)u) << 16);
}

// rocPRIM-pattern wave64 sum via DPP (VALU-only, no LDS pipe). Sum -> lane 63.
__device__ __forceinline__ float dpp_add(float x) {
  x += __int_as_float(__builtin_amdgcn_update_dpp(0, __float_as_int(x), 0x111, 0xf, 0xf, false)); // row_shr:1
  x += __int_as_float(__builtin_amdgcn_update_dpp(0, __float_as_int(x), 0x112, 0xf, 0xf, false)); // row_shr:2
  x += __int_as_float(__builtin_amdgcn_update_dpp(0, __float_as_int(x), 0x114, 0xf, 0xe, false)); // row_shr:4
  x += __int_as_float(__builtin_amdgcn_update_dpp(0, __float_as_int(x), 0x118, 0xf, 0xc, false)); // row_shr:8
  x += __int_as_float(__builtin_amdgcn_update_dpp(0, __float_as_int(x), 0x142, 0xa, 0xf, false)); // row_bcast:15
  x += __int_as_float(__builtin_amdgcn_update_dpp(0, __float_as_int(x), 0x143, 0xc, 0xf, false)); // row_bcast:31
  return x;
}

#define GLD_LDS16(gp, lp)                                                     \
  __builtin_amdgcn_global_load_lds(                                           \
      (const __attribute__((address_space(1))) void*)(gp),                    \
      (__attribute__((address_space(3))) void*)(lp), 16, 0, 0)

// ---------------------------------------------------------------------------
// K0 (blocks 0..1023): W_sub f32 [k][n] -> Wt bf16 [n][k] transpose (first).
// K1 (blocks 1024..9215): per-(b,s) LN stats + h_avg (bf16) + beta GEMV.
// (R10-proven — FROZEN. Measured R14: 21.9 µs ≈ HBM floor.)
// ---------------------------------------------------------------------------
__global__ __launch_bounds__(256) void k_pre(
    const float* __restrict__ h,       // (8192, 4, 1024)
    const float* __restrict__ ln_g,    // (1024)
    const float* __restrict__ ln_b,    // (1024)
    const float* __restrict__ dbf,     // (1024, 4)
    const float* __restrict__ dbs,     // (1)
    const float* __restrict__ sbeta,   // (4)
    const float* __restrict__ W,       // (1024, 1024)
    unsigned short* __restrict__ havg, // (8192, 1024) bf16
    float* __restrict__ beta_out,      // (8192, 4)
    unsigned short* __restrict__ Wt)   // (1024, 1024) bf16 transposed
{
  __shared__ float shmem[32 * 33];
  const int t = threadIdx.x;

  if (blockIdx.x < 1024) {
    // ---- W transpose (runs first) ----
    const int b = blockIdx.x;
    const int bn = b & 31, bk = b >> 5;
    float (*tile)[33] = (float (*)[33])shmem;
    const int tx = t & 31, ty = t >> 5;
#pragma unroll
    for (int r = ty; r < 32; r += 8)
      tile[r][tx] = W[(size_t)(bk * 32 + r) * 1024 + bn * 32 + tx];
    __syncthreads();
#pragma unroll
    for (int r = ty; r < 32; r += 8)
      Wt[(size_t)(bn * 32 + r) * 1024 + bk * 32 + tx] = f2bf(tile[tx][r]);
    return;
  }

  const int bs = blockIdx.x - 1024;
  const int lane = t & 63, wid = t >> 6;
  float (*sm)[8] = (float (*)[8])shmem;
  const float* hrow = h + (size_t)bs * 4096;
  const int d0 = t * 4;

  float x[4][4];
  float red[8];
#pragma unroll
  for (int n = 0; n < 4; ++n) {
    float4 v = *(const float4*)(hrow + n * 1024 + d0);
    x[n][0] = v.x; x[n][1] = v.y; x[n][2] = v.z; x[n][3] = v.w;
    red[n] = v.x + v.y + v.z + v.w;
    red[4 + n] = v.x * v.x + v.y * v.y + v.z * v.z + v.w * v.w;
  }
#pragma unroll
  for (int k = 0; k < 8; ++k) red[k] = dpp_add(red[k]);
  if (lane == 63) {
#pragma unroll
    for (int k = 0; k < 8; ++k) sm[wid][k] = red[k];
  }
  __syncthreads();
  float mean[4], rstd[4];
#pragma unroll
  for (int n = 0; n < 4; ++n) {
    float s = sm[0][n] + sm[1][n] + sm[2][n] + sm[3][n];
    float sq = sm[0][4 + n] + sm[1][4 + n] + sm[2][4 + n] + sm[3][4 + n];
    float m = s * (1.0f / 1024.0f);
    float var = sq * (1.0f / 1024.0f) - m * m;
    mean[n] = m;
    rstd[n] = rsqrtf(var + 1e-5f);
  }
  const float4 g4 = *(const float4*)(ln_g + d0);
  const float4 b4 = *(const float4*)(ln_b + d0);
  const float gg[4] = {g4.x, g4.y, g4.z, g4.w};
  const float bb[4] = {b4.x, b4.y, b4.z, b4.w};

  float nm[4];
  ushort4 pack;
  unsigned short* pk = (unsigned short*)&pack;
#pragma unroll
  for (int j = 0; j < 4; ++j) {
    float sh = 0.f, sn = 0.f;
#pragma unroll
    for (int n = 0; n < 4; ++n) {
      sh += x[n][j];
      sn += (x[n][j] - mean[n]) * rstd[n];
    }
    pk[j] = f2bf(0.25f * sh);               // h_avg = mix_h row (i-independent)
    nm[j] = 0.25f * sn * gg[j] + bb[j];     // norm_h_mean
  }
  *(ushort4*)(havg + (size_t)bs * 1024 + d0) = pack;

  // beta = tanh(nm @ dbf) * scale + static_beta
  float a4[4] = {0.f, 0.f, 0.f, 0.f};
#pragma unroll
  for (int j = 0; j < 4; ++j) {
    const float4 w = *(const float4*)(dbf + (size_t)(d0 + j) * 4);
    a4[0] += nm[j] * w.x; a4[1] += nm[j] * w.y;
    a4[2] += nm[j] * w.z; a4[3] += nm[j] * w.w;
  }
#pragma unroll
  for (int c = 0; c < 4; ++c) a4[c] = dpp_add(a4[c]);
  __syncthreads();  // all stats reads done before sm re-write
  if (lane == 63) {
#pragma unroll
    for (int c = 0; c < 4; ++c) sm[wid][c] = a4[c];
  }
  __syncthreads();
  if (t == 0) {
    const float sc = dbs[0];
#pragma unroll
    for (int c = 0; c < 4; ++c) {
      float dot = sm[0][c] + sm[1][c] + sm[2][c] + sm[3][c];
      beta_out[(size_t)bs * 4 + c] = tanhf(dot) * sc + sbeta[c];
    }
  }
}

// ---------------------------------------------------------------------------
// K2: h_o = h_avg @ W  (M=8192, N=1024, K=1024)
//     THIS ROUND: 64x128 tiles -> grid (128,8) = 1024 blocks = 4 blocks/CU.
//     Same R10 loop structure (stage-all -> one drain -> MFMAs -> barrier,
//     BK=64, 16 iters). A-amplification stays 8x (as R10); B is the 2 MB
//     L2-resident panel; A-sharers are XCD-local by construction
//     ((nblk*128+mblk)%8 == mblk%8). 4-way block TLP hides store bursts
//     and drain stalls (the overlap R15's intra-block split couldn't give:
//     __syncthreads drains stores too).
//     LDS 24 KB, acc 2x4 frags = 32 VGPR.
//     epilogue: out[m][i][n] = beta[m][i]*h_o[m][n] + h_avg[m][n]
// ---------------------------------------------------------------------------
__global__ __launch_bounds__(256) void k_gemm_ep(
    const unsigned short* __restrict__ A,   // (8192,1024) bf16  h_avg
    const unsigned short* __restrict__ Bt,  // (1024,1024) bf16  Wt[n][k]
    const float* __restrict__ beta4,        // (8192,4)
    float* __restrict__ out)                // (8192,4,1024)
{
  __shared__ unsigned short As[2][64][32];   //  8 KB
  __shared__ unsigned short Bs[2][128][32];  // 16 KB
  const int t = threadIdx.x;
  const int wid = t >> 6, lane = t & 63;
  const int mblk = blockIdx.x, nblk = blockIdx.y;
  const int wr = wid >> 1, wc = wid & 1;      // 2x2 waves, 32x64 each
  const int l15 = lane & 15, kg = lane >> 4;  // fragment coords

  f32x4 acc[2][4] = {};

  const int srow = t >> 2;                    // 0..63
  const int sk8 = (t & 3) * 8;
  const unsigned short* gA = A + (size_t)(mblk * 64 + srow) * 1024 + sk8;
  const unsigned short* gB = Bt + (size_t)(nblk * 128 + srow) * 1024 + sk8;
  char* ldsA = (char*)As + wid * 1024;  // wave-uniform base
  char* ldsB = (char*)Bs + wid * 1024;

  for (int kt2 = 0; kt2 < 16; ++kt2) {
    const int ko = kt2 * 64;
    // stage both 32-wide sub-tiles (A: 2 GLDs, B: 4 GLDs), one drain barrier
#pragma unroll
    for (int s = 0; s < 2; ++s) {
      GLD_LDS16(gA + ko + s * 32, ldsA + s * 4096);
      GLD_LDS16(gB + ko + s * 32, ldsB + s * 8192);
      GLD_LDS16(gB + 64 * 1024 + ko + s * 32, ldsB + s * 8192 + 4096);
    }
    __syncthreads();
#pragma unroll
    for (int sub = 0; sub < 2; ++sub) {
      bf16x8 a[2], b[4];
#pragma unroll
      for (int mi = 0; mi < 2; ++mi)
        a[mi] = *(const bf16x8*)(&As[sub][wr * 32 + mi * 16 + l15][kg * 8]);
#pragma unroll
      for (int ni = 0; ni < 4; ++ni)
        b[ni] = *(const bf16x8*)(&Bs[sub][wc * 64 + ni * 16 + l15][kg * 8]);
#pragma unroll
      for (int mi = 0; mi < 2; ++mi)
#pragma unroll
        for (int ni = 0; ni < 4; ++ni)
          acc[mi][ni] =
              __builtin_amdgcn_mfma_f32_16x16x32_bf16(a[mi], b[ni], acc[mi][ni], 0, 0, 0);
    }
    __syncthreads();
  }

  // epilogue: D row = 4*(lane>>4)+reg, col = lane&15 within each 16x16 frag
  const int rbase = mblk * 64 + wr * 32 + kg * 4;
  const int cbase = nblk * 128 + wc * 64 + l15;
#pragma unroll
  for (int mi = 0; mi < 2; ++mi) {
    float4 be[4];
#pragma unroll
    for (int r = 0; r < 4; ++r)
      be[r] = *(const float4*)(beta4 + (size_t)(rbase + mi * 16 + r) * 4);
#pragma unroll
    for (int ni = 0; ni < 4; ++ni) {
      const int col = cbase + ni * 16;
#pragma unroll
      for (int r = 0; r < 4; ++r) {
        const int row = rbase + mi * 16 + r;
        const float ho = acc[mi][ni][r];
        const float hv = bf2f(A[(size_t)row * 1024 + col]);
        const float4 bq = be[r];
        float* o = out + (size_t)row * 4096 + col;
        o[0]    = bq.x * ho + hv;
        o[1024] = bq.y * ho + hv;
        o[2048] = bq.z * ho + hv;
        o[3072] = bq.w * ho + hv;
      }
    }
  }
}

extern "C" void kernel_launch(void* const* d_in, const int* in_sizes, int n_in,
                              void* d_out, int out_size, void* d_ws, size_t ws_size,
                              hipStream_t stream) {
  const float* h     = (const float*)d_in[0];
  // d_in[1] static_alpha, d_in[3] dynamic_alpha_fn, d_in[4] dynamic_alpha_scale:
  // dead — Sinkhorn output is exactly 1/n for this broadcast-structured alpha.
  const float* sbeta = (const float*)d_in[2];
  const float* dbf   = (const float*)d_in[5];
  const float* dbs   = (const float*)d_in[6];
  const float* ln_g  = (const float*)d_in[7];
  const float* ln_b  = (const float*)d_in[8];
  const float* W     = (const float*)d_in[9];
  float* out = (float*)d_out;

  char* ws = (char*)d_ws;
  unsigned short* havg = (unsigned short*)ws;                  // 16 MB
  unsigned short* Wt   = (unsigned short*)(ws + (16u << 20));  // 2 MB
  float* beta          = (float*)(ws + (18u << 20));           // 128 KB

  hipLaunchKernelGGL(k_pre, dim3(1024 + 8192), dim3(256), 0, stream,
                     h, ln_g, ln_b, dbf, dbs, sbeta, W, havg, beta, Wt);
  hipLaunchKernelGGL(k_gemm_ep, dim3(128, 8), dim3(256), 0, stream,
                     havg, Wt, beta, out);
}

// Round 17
// 80.682 us; speedup vs baseline: 1.3649x; 1.0290x over previous
//
#include <hip/hip_runtime.h>

typedef short bf16x8 __attribute__((ext_vector_type(8)));
typedef float f32x4 __attribute__((ext_vector_type(4)));

__device__ __forceinline__ unsigned short f2bf(float f) {
  unsigned int x = __float_as_uint(f);
  x += 0x7fffu + ((x >> 16) & 1u);
  return (unsigned short)(x >> 16);
}
__device__ __forceinline__ float bf2f(unsigned short u) {
  return __uint_as_float(((unsigned int)u) << 16);
}

// rocPRIM-pattern wave64 sum via DPP (VALU-only, no LDS pipe). Sum -> lane 63.
__device__ __forceinline__ float dpp_add(float x) {
  x += __int_as_float(__builtin_amdgcn_update_dpp(0, __float_as_int(x), 0x111, 0xf, 0xf, false)); // row_shr:1
  x += __int_as_float(__builtin_amdgcn_update_dpp(0, __float_as_int(x), 0x112, 0xf, 0xf, false)); // row_shr:2
  x += __int_as_float(__builtin_amdgcn_update_dpp(0, __float_as_int(x), 0x114, 0xf, 0xe, false)); // row_shr:4
  x += __int_as_float(__builtin_amdgcn_update_dpp(0, __float_as_int(x), 0x118, 0xf, 0xc, false)); // row_shr:8
  x += __int_as_float(__builtin_amdgcn_update_dpp(0, __float_as_int(x), 0x142, 0xa, 0xf, false)); // row_bcast:15
  x += __int_as_float(__builtin_amdgcn_update_dpp(0, __float_as_int(x), 0x143, 0xc, 0xf, false)); // row_bcast:31
  return x;
}

#define GLD_LDS16(gp, lp)                                                     \
  __builtin_amdgcn_global_load_lds(                                           \
      (const __attribute__((address_space(1))) void*)(gp),                    \
      (__attribute__((address_space(3))) void*)(lp), 16, 0, 0)

// ---------------------------------------------------------------------------
// K0 (blocks 0..1023): W_sub f32 [k][n] -> Wt bf16 [n][k] transpose (first).
// K1 (blocks 1024..9215): per-(b,s) LN stats + h_avg (bf16) + beta GEMV.
// (R10-proven. Measured R14: 21.9 µs ≈ HBM floor.)
// ---------------------------------------------------------------------------
__global__ __launch_bounds__(256) void k_pre(
    const float* __restrict__ h,       // (8192, 4, 1024)
    const float* __restrict__ ln_g,    // (1024)
    const float* __restrict__ ln_b,    // (1024)
    const float* __restrict__ dbf,     // (1024, 4)
    const float* __restrict__ dbs,     // (1)
    const float* __restrict__ sbeta,   // (4)
    const float* __restrict__ W,       // (1024, 1024)
    unsigned short* __restrict__ havg, // (8192, 1024) bf16
    float* __restrict__ beta_out,      // (8192, 4)
    unsigned short* __restrict__ Wt)   // (1024, 1024) bf16 transposed
{
  __shared__ float shmem[32 * 33];
  const int t = threadIdx.x;

  if (blockIdx.x < 1024) {
    // ---- W transpose (runs first) ----
    const int b = blockIdx.x;
    const int bn = b & 31, bk = b >> 5;
    float (*tile)[33] = (float (*)[33])shmem;
    const int tx = t & 31, ty = t >> 5;
#pragma unroll
    for (int r = ty; r < 32; r += 8)
      tile[r][tx] = W[(size_t)(bk * 32 + r) * 1024 + bn * 32 + tx];
    __syncthreads();
#pragma unroll
    for (int r = ty; r < 32; r += 8)
      Wt[(size_t)(bn * 32 + r) * 1024 + bk * 32 + tx] = f2bf(tile[tx][r]);
    return;
  }

  const int bs = blockIdx.x - 1024;
  const int lane = t & 63, wid = t >> 6;
  float (*sm)[8] = (float (*)[8])shmem;
  const float* hrow = h + (size_t)bs * 4096;
  const int d0 = t * 4;

  float x[4][4];
  float red[8];
#pragma unroll
  for (int n = 0; n < 4; ++n) {
    float4 v = *(const float4*)(hrow + n * 1024 + d0);
    x[n][0] = v.x; x[n][1] = v.y; x[n][2] = v.z; x[n][3] = v.w;
    red[n] = v.x + v.y + v.z + v.w;
    red[4 + n] = v.x * v.x + v.y * v.y + v.z * v.z + v.w * v.w;
  }
#pragma unroll
  for (int k = 0; k < 8; ++k) red[k] = dpp_add(red[k]);
  if (lane == 63) {
#pragma unroll
    for (int k = 0; k < 8; ++k) sm[wid][k] = red[k];
  }
  __syncthreads();
  float mean[4], rstd[4];
#pragma unroll
  for (int n = 0; n < 4; ++n) {
    float s = sm[0][n] + sm[1][n] + sm[2][n] + sm[3][n];
    float sq = sm[0][4 + n] + sm[1][4 + n] + sm[2][4 + n] + sm[3][4 + n];
    float m = s * (1.0f / 1024.0f);
    float var = sq * (1.0f / 1024.0f) - m * m;
    mean[n] = m;
    rstd[n] = rsqrtf(var + 1e-5f);
  }
  const float4 g4 = *(const float4*)(ln_g + d0);
  const float4 b4 = *(const float4*)(ln_b + d0);
  const float gg[4] = {g4.x, g4.y, g4.z, g4.w};
  const float bb[4] = {b4.x, b4.y, b4.z, b4.w};

  float nm[4];
  ushort4 pack;
  unsigned short* pk = (unsigned short*)&pack;
#pragma unroll
  for (int j = 0; j < 4; ++j) {
    float sh = 0.f, sn = 0.f;
#pragma unroll
    for (int n = 0; n < 4; ++n) {
      sh += x[n][j];
      sn += (x[n][j] - mean[n]) * rstd[n];
    }
    pk[j] = f2bf(0.25f * sh);               // h_avg = mix_h row (i-independent)
    nm[j] = 0.25f * sn * gg[j] + bb[j];     // norm_h_mean
  }
  *(ushort4*)(havg + (size_t)bs * 1024 + d0) = pack;

  // beta = tanh(nm @ dbf) * scale + static_beta
  float a4[4] = {0.f, 0.f, 0.f, 0.f};
#pragma unroll
  for (int j = 0; j < 4; ++j) {
    const float4 w = *(const float4*)(dbf + (size_t)(d0 + j) * 4);
    a4[0] += nm[j] * w.x; a4[1] += nm[j] * w.y;
    a4[2] += nm[j] * w.z; a4[3] += nm[j] * w.w;
  }
#pragma unroll
  for (int c = 0; c < 4; ++c) a4[c] = dpp_add(a4[c]);
  __syncthreads();  // all stats reads done before sm re-write
  if (lane == 63) {
#pragma unroll
    for (int c = 0; c < 4; ++c) sm[wid][c] = a4[c];
  }
  __syncthreads();
  if (t == 0) {
    const float sc = dbs[0];
#pragma unroll
    for (int c = 0; c < 4; ++c) {
      float dot = sm[0][c] + sm[1][c] + sm[2][c] + sm[3][c];
      beta_out[(size_t)bs * 4 + c] = tanhf(dot) * sc + sbeta[c];
    }
  }
}

// ---------------------------------------------------------------------------
// K2: h_o = h_avg @ W  (M=8192, N=1024, K=1024, 128x128 tile, BK=64)
//     R10-proven structure — session optimum (81.4 µs total), restored
//     verbatim. Stage 8 GLDs -> ONE drain barrier -> 2x16 MFMA -> barrier.
//     epilogue: out[m][i][n] = beta[m][i]*h_o[m][n] + h_avg[m][n]
// ---------------------------------------------------------------------------
__global__ __launch_bounds__(256) void k_gemm_ep(
    const unsigned short* __restrict__ A,   // (8192,1024) bf16  h_avg
    const unsigned short* __restrict__ Bt,  // (1024,1024) bf16  Wt[n][k]
    const float* __restrict__ beta4,        // (8192,4)
    float* __restrict__ out)                // (8192,4,1024)
{
  __shared__ unsigned short As[2][128][32];
  __shared__ unsigned short Bs[2][128][32];
  const int t = threadIdx.x;
  const int wid = t >> 6, lane = t & 63;
  const int mblk = blockIdx.x, nblk = blockIdx.y;
  const int wr = wid >> 1, wc = wid & 1;      // 2x2 waves, 64x64 each
  const int l15 = lane & 15, kg = lane >> 4;  // fragment coords

  f32x4 acc[4][4] = {};

  const int srow = t >> 2;
  const int sk8 = (t & 3) * 8;
  const unsigned short* gA = A + (size_t)(mblk * 128 + srow) * 1024 + sk8;
  const unsigned short* gB = Bt + (size_t)(nblk * 128 + srow) * 1024 + sk8;
  char* ldsA = (char*)As + wid * 1024;  // wave-uniform base
  char* ldsB = (char*)Bs + wid * 1024;

  for (int kt2 = 0; kt2 < 16; ++kt2) {
    const int ko = kt2 * 64;
    // stage BOTH 32-wide sub-tiles, then a single drain barrier
    GLD_LDS16(gA + ko, ldsA);
    GLD_LDS16(gA + 64 * 1024 + ko, ldsA + 4096);
    GLD_LDS16(gA + ko + 32, ldsA + 8192);
    GLD_LDS16(gA + 64 * 1024 + ko + 32, ldsA + 8192 + 4096);
    GLD_LDS16(gB + ko, ldsB);
    GLD_LDS16(gB + 64 * 1024 + ko, ldsB + 4096);
    GLD_LDS16(gB + ko + 32, ldsB + 8192);
    GLD_LDS16(gB + 64 * 1024 + ko + 32, ldsB + 8192 + 4096);
    __syncthreads();
#pragma unroll
    for (int sub = 0; sub < 2; ++sub) {
      bf16x8 a[4], b[4];
#pragma unroll
      for (int mi = 0; mi < 4; ++mi)
        a[mi] = *(const bf16x8*)(&As[sub][wr * 64 + mi * 16 + l15][kg * 8]);
#pragma unroll
      for (int ni = 0; ni < 4; ++ni)
        b[ni] = *(const bf16x8*)(&Bs[sub][wc * 64 + ni * 16 + l15][kg * 8]);
#pragma unroll
      for (int mi = 0; mi < 4; ++mi)
#pragma unroll
        for (int ni = 0; ni < 4; ++ni)
          acc[mi][ni] =
              __builtin_amdgcn_mfma_f32_16x16x32_bf16(a[mi], b[ni], acc[mi][ni], 0, 0, 0);
    }
    __syncthreads();
  }

  // epilogue: D row = 4*(lane>>4)+reg, col = lane&15 within each 16x16 frag
  const int rbase = mblk * 128 + wr * 64 + kg * 4;
  const int cbase = nblk * 128 + wc * 64 + l15;
#pragma unroll
  for (int mi = 0; mi < 4; ++mi) {
    float4 be[4];
#pragma unroll
    for (int r = 0; r < 4; ++r)
      be[r] = *(const float4*)(beta4 + (size_t)(rbase + mi * 16 + r) * 4);
#pragma unroll
    for (int ni = 0; ni < 4; ++ni) {
      const int col = cbase + ni * 16;
#pragma unroll
      for (int r = 0; r < 4; ++r) {
        const int row = rbase + mi * 16 + r;
        const float ho = acc[mi][ni][r];
        const float hv = bf2f(A[(size_t)row * 1024 + col]);
        const float4 bq = be[r];
        float* o = out + (size_t)row * 4096 + col;
        o[0]    = bq.x * ho + hv;
        o[1024] = bq.y * ho + hv;
        o[2048] = bq.z * ho + hv;
        o[3072] = bq.w * ho + hv;
      }
    }
  }
}

extern "C" void kernel_launch(void* const* d_in, const int* in_sizes, int n_in,
                              void* d_out, int out_size, void* d_ws, size_t ws_size,
                              hipStream_t stream) {
  const float* h     = (const float*)d_in[0];
  // d_in[1] static_alpha, d_in[3] dynamic_alpha_fn, d_in[4] dynamic_alpha_scale:
  // dead — Sinkhorn output is exactly 1/n for this broadcast-structured alpha.
  const float* sbeta = (const float*)d_in[2];
  const float* dbf   = (const float*)d_in[5];
  const float* dbs   = (const float*)d_in[6];
  const float* ln_g  = (const float*)d_in[7];
  const float* ln_b  = (const float*)d_in[8];
  const float* W     = (const float*)d_in[9];
  float* out = (float*)d_out;

  char* ws = (char*)d_ws;
  unsigned short* havg = (unsigned short*)ws;                  // 16 MB
  unsigned short* Wt   = (unsigned short*)(ws + (16u << 20));  // 2 MB
  float* beta          = (float*)(ws + (18u << 20));           // 128 KB

  hipLaunchKernelGGL(k_pre, dim3(1024 + 8192), dim3(256), 0, stream,
                     h, ln_g, ln_b, dbf, dbs, sbeta, W, havg, beta, Wt);
  hipLaunchKernelGGL(k_gemm_ep, dim3(64, 8), dim3(256), 0, stream,
                     havg, Wt, beta, out);
}